// Round 1
// baseline (471.748 us; speedup 1.0000x reference)
//
#include <hip/hip_runtime.h>
#include <math.h>

#define TT 512
#define BB 512
#define CC 32
#define CIN 33
#define HH 128
#define EPSF 1e-12f
#define CH 16              // timesteps per gx-chunk staged in LDS
#define NCH (TT / CH)
#define RB 2               // batch rows per block
#define HSP 160            // hs row stride (halves): 320 B == 16 banks -> rows disjoint
#define GXP 520            // gx row stride (floats): 512+8 -> rows 8 banks apart

typedef _Float16 half8 __attribute__((ext_vector_type(8)));
typedef _Float16 half2v __attribute__((ext_vector_type(2)));
typedef float f32x4 __attribute__((ext_vector_type(4)));

#define MFMA16H(a, b, c) __builtin_amdgcn_mfma_f32_16x16x32_f16(a, b, c, 0, 0, 0)
// In-loop barrier: LDS visibility only. Deliberately NO vmcnt drain so the
// chunk-staging global loads stay in flight across step barriers (the
// __syncthreads() form emits s_waitcnt vmcnt(0) and eats ~900cyc once/chunk).
#define BARRIER() asm volatile("s_waitcnt lgkmcnt(0)\n\ts_barrier" ::: "memory")

__device__ __forceinline__ float fsig(float x) {
    return __builtin_amdgcn_rcpf(1.f + __expf(-x));
}
__device__ __forceinline__ float ftanh(float x) {
    return 1.f - 2.f * __builtin_amdgcn_rcpf(1.f + __expf(2.f * x));
}
// full-wave (64) sum via DPP; result valid on lane 63 ONLY.
__device__ __forceinline__ float wave_sum_dpp(float x) {
    x += __int_as_float(__builtin_amdgcn_update_dpp(0, __float_as_int(x), 0x111, 0xf, 0xf, true));
    x += __int_as_float(__builtin_amdgcn_update_dpp(0, __float_as_int(x), 0x112, 0xf, 0xf, true));
    x += __int_as_float(__builtin_amdgcn_update_dpp(0, __float_as_int(x), 0x114, 0xf, 0xf, true));
    x += __int_as_float(__builtin_amdgcn_update_dpp(0, __float_as_int(x), 0x118, 0xf, 0xf, true));
    x += __int_as_float(__builtin_amdgcn_update_dpp(0, __float_as_int(x), 0x142, 0xa, 0xf, true));
    x += __int_as_float(__builtin_amdgcn_update_dpp(0, __float_as_int(x), 0x143, 0xc, 0xf, true));
    return x;
}
// sum within each 16-lane row; result valid on lanes 15/31/47/63.
__device__ __forceinline__ float row_sum_dpp(float x) {
    x += __int_as_float(__builtin_amdgcn_update_dpp(0, __float_as_int(x), 0x111, 0xf, 0xf, true));
    x += __int_as_float(__builtin_amdgcn_update_dpp(0, __float_as_int(x), 0x112, 0xf, 0xf, true));
    x += __int_as_float(__builtin_amdgcn_update_dpp(0, __float_as_int(x), 0x114, 0xf, 0xf, true));
    x += __int_as_float(__builtin_amdgcn_update_dpp(0, __float_as_int(x), 0x118, 0xf, 0xf, true));
    return x;
}
// spin-load ws[t]: ws is 0xAA-poisoned each launch (sentinel). Relaxed order is
// sufficient: the 4-byte value IS the data; AGENT scope gives cross-XCD
// visibility.
__device__ __forceinline__ float load_s(const float* p) {
    float v = __hip_atomic_load(p, __ATOMIC_RELAXED, __HIP_MEMORY_SCOPE_AGENT);
    for (int it = 0; it < 100000000 && __float_as_uint(v) == 0xAAAAAAAAu; ++it)
        v = __hip_atomic_load(p, __ATOMIC_RELAXED, __HIP_MEMORY_SCOPE_AGENT);
    return v;
}

// ---------------------------------------------------------------------------
// R19: x-projection moved OUT of the per-step path. Per 16-step chunk, the
// gates_x for 32 (t,row) pairs are computed as two full-16-row MFMA tiles per
// p-group (8 MFMA/wave/chunk vs the previous 4/wave/STEP = 64/chunk), with
// bias + minibatch-std term folded in, stored f32 in LDS (gxs). Inner step:
// 16 MFMA/wave (h-part only) + 4 ds_read_b32 of gx. Staging is split T14
// style: global loads issue at chunk start, MFMA+commit at k=8. In-loop
// barriers are raw lgkmcnt-only (no vmcnt drain).
// ---------------------------------------------------------------------------
__global__ __attribute__((amdgpu_flat_work_group_size(512, 512), amdgpu_waves_per_eu(2, 2)))
void critic_fused(
    const float* __restrict__ x,
    const float* __restrict__ w_ih, const float* __restrict__ u_ih,
    const float* __restrict__ w_hh, const float* __restrict__ u_hh,
    const float* __restrict__ b_ih, const float* __restrict__ b_hh,
    const float* __restrict__ attn_w, const float* __restrict__ attn_b,
    const float* __restrict__ fc_w, const float* __restrict__ u_fc,
    const float* __restrict__ fc_b,
    float* __restrict__ ws,
    float* __restrict__ out)
{
    const int tid = threadIdx.x;
    const int w   = tid >> 6;          // wave 0..7
    const int l   = tid & 63;          // lane
    const int m   = l & 15;            // A-row / B-col index
    const int q   = l >> 4;            // quad 0..3
    const int r   = q & 1;             // this lane's batch row (duplicated rows)
    const int b0  = blockIdx.x * RB;
    const int jcol = 16 * w + m;       // this lane's h column

    // ---- LDS ----
    __shared__ float4 sSS[2][8][8];                         // std wave-partials per tt
    __shared__ float4 sQQ[2][8][8];
    __shared__ float stdp[2][8];                            // per-c4 std partials
    __shared__ float red[512];                              // sigma scratch
    __shared__ float vv[128];
    __shared__ float sigS[3];                               // sig_ih, sig_hh, sig_fc
    __shared__ __align__(16) _Float16 hs[2][RB][HSP];       // h planes
    __shared__ float gxs[2][2 * CH][GXP];                   // gates_x chunks, row=2k+rr
    __shared__ __align__(8) float bcast[2][RB];             // beta per row
    __shared__ float Sf[RB];
    __shared__ float part[8][RB];                           // FC partials

    // ===== Phase A loads issued FIRST (HBM latency hidden by phase B) =====
    const int c4 = tid & 7;       // c = c4*4 .. c4*4+3
    const int bs = tid >> 3;      // 64 groups of 8 batch rows
    float4 xa[2][8];
#pragma unroll
    for (int tt = 0; tt < 2; ++tt) {
        const int t = 2 * blockIdx.x + tt;
#pragma unroll
        for (int i = 0; i < 8; ++i)
            xa[tt][i] = *reinterpret_cast<const float4*>(
                x + ((size_t)(bs * 8 + i) * TT + t) * CC + c4 * 4);
    }

    // ===== sigma_hh projection in the loads' shadow (L2-bound) =====
    {
        const int c = tid & 127, qq = tid >> 7;
        const float* wp = w_hh + (size_t)(qq * 128) * HH + c;
        const float* up = u_hh + qq * 128;
        float a0 = 0.f, a1 = 0.f, a2 = 0.f, a3 = 0.f;
#pragma unroll 4
        for (int g = 0; g < 128; g += 4) {
            a0 = fmaf(wp[(size_t)(g + 0) * HH], up[g + 0], a0);
            a1 = fmaf(wp[(size_t)(g + 1) * HH], up[g + 1], a1);
            a2 = fmaf(wp[(size_t)(g + 2) * HH], up[g + 2], a2);
            a3 = fmaf(wp[(size_t)(g + 3) * HH], up[g + 3], a3);
        }
        red[tid] = (a0 + a1) + (a2 + a3);
    }

    // ===== Phase A reduction (registers already landed) =====
#pragma unroll
    for (int tt = 0; tt < 2; ++tt) {
        float4 S = make_float4(0.f, 0.f, 0.f, 0.f);
        float4 Q = make_float4(0.f, 0.f, 0.f, 0.f);
#pragma unroll
        for (int i = 0; i < 8; ++i) {
            float4 v = xa[tt][i];
            S.x += v.x; S.y += v.y; S.z += v.z; S.w += v.w;
            Q.x = fmaf(v.x, v.x, Q.x); Q.y = fmaf(v.y, v.y, Q.y);
            Q.z = fmaf(v.z, v.z, Q.z); Q.w = fmaf(v.w, v.w, Q.w);
        }
#pragma unroll
        for (int off = 8; off <= 32; off <<= 1) {
            S.x += __shfl_xor(S.x, off, 64); S.y += __shfl_xor(S.y, off, 64);
            S.z += __shfl_xor(S.z, off, 64); S.w += __shfl_xor(S.w, off, 64);
            Q.x += __shfl_xor(Q.x, off, 64); Q.y += __shfl_xor(Q.y, off, 64);
            Q.z += __shfl_xor(Q.z, off, 64); Q.w += __shfl_xor(Q.w, off, 64);
        }
        if (l < 8) { sSS[tt][w][c4] = S; sQQ[tt][w][c4] = Q; }
    }
    __syncthreads();   // publishes red[] (projection) + sSS/sQQ

    // disjoint groups: tid<128 -> vv combine; tid 384..399 -> std combine
    if (tid < 128) vv[tid] = red[tid] + red[tid + 128] + red[tid + 256] + red[tid + 384];
    if (tid >= 384 && tid < 400) {
        const int tt2 = (tid - 384) >> 3, cc = (tid - 384) & 7;
        float4 St = make_float4(0.f, 0.f, 0.f, 0.f);
        float4 Qt = make_float4(0.f, 0.f, 0.f, 0.f);
#pragma unroll
        for (int i = 0; i < 8; ++i) {
            float4 a = sSS[tt2][i][cc], b4 = sQQ[tt2][i][cc];
            St.x += a.x; St.y += a.y; St.z += a.z; St.w += a.w;
            Qt.x += b4.x; Qt.y += b4.y; Qt.z += b4.z; Qt.w += b4.w;
        }
        float st = 0.f;
#pragma unroll
        for (int i = 0; i < 4; ++i) {
            float s1 = (i == 0) ? St.x : (i == 1) ? St.y : (i == 2) ? St.z : St.w;
            float q1 = (i == 0) ? Qt.x : (i == 1) ? Qt.y : (i == 2) ? Qt.z : Qt.w;
            float mean = s1 / 512.0f;
            float var  = (q1 - 512.0f * mean * mean) / 511.0f;
            st += sqrtf(fmaxf(var, 0.f));
        }
        stdp[tt2][cc] = st;
    }
    __syncthreads();
    // tid 408/409: publish ws[t]; tid<512: square vv for norm reduction
    if (tid >= 408 && tid < 410) {
        const int tt2 = tid - 408;
        float mm = 0.f;
#pragma unroll
        for (int i = 0; i < 8; ++i) mm += stdp[tt2][i];
        __hip_atomic_store(&ws[2 * blockIdx.x + tt2], mm / 32.0f, __ATOMIC_RELAXED,
                           __HIP_MEMORY_SCOPE_AGENT);
    }
    red[tid] = (tid < 128) ? vv[tid] * vv[tid] : 0.f;
    __syncthreads();

    // ===== sigma_hh: norm + W@v =====
    {
        for (int s = 64; s >= 1; s >>= 1) { if (tid < s) red[tid] += red[tid + s]; __syncthreads(); }
        const float nv = sqrtf(red[0]);
        __syncthreads();
        if (tid < 128) vv[tid] = vv[tid] / (nv + EPSF);
        __syncthreads();
        float sq = 0.f;
        float2 vl = *reinterpret_cast<const float2*>(&vv[2 * l]);
#pragma unroll 4
        for (int gi = 0; gi < 64; ++gi) {
            const int g = w * 64 + gi;
            float2 wl = *reinterpret_cast<const float2*>(&w_hh[(size_t)g * HH + 2 * l]);
            float p  = fmaf(wl.x, vl.x, wl.y * vl.y);
            float tot = wave_sum_dpp(p);
            sq = fmaf(tot, tot, sq);
        }
        if (l == 63) red[w] = sq;
        __syncthreads();
        if (tid == 0) {
            float ns2 = 0.f;
            for (int i = 0; i < 8; ++i) ns2 += red[i];
            sigS[1] = ns2 / (sqrtf(ns2) + EPSF);
        }
        __syncthreads();
    }
    // ===== sigma_ih =====
    {
        if (l < CIN) {
            float a0 = 0.f, a1 = 0.f;
#pragma unroll 4
            for (int gi = 0; gi < 64; gi += 2) {
                const int g = w * 64 + gi;
                a0 = fmaf(w_ih[(size_t)(g + 0) * CIN + l], u_ih[g + 0], a0);
                a1 = fmaf(w_ih[(size_t)(g + 1) * CIN + l], u_ih[g + 1], a1);
            }
            red[w * 64 + l] = a0 + a1;
        }
        __syncthreads();
        if (tid < CIN) {
            float v = 0.f;
#pragma unroll
            for (int i = 0; i < 8; ++i) v += red[i * 64 + tid];
            vv[tid] = v;
        }
        __syncthreads();
        if (tid == 0) {
            float n2 = 0.f;
            for (int i = 0; i < CIN; ++i) n2 += vv[i] * vv[i];
            red[400] = sqrtf(n2);
        }
        __syncthreads();
        const float nv = red[400];
        if (tid < CIN) vv[tid] = vv[tid] / (nv + EPSF);
        __syncthreads();
        float vl = (l < CIN) ? vv[l] : 0.f;
        float sq = 0.f;
#pragma unroll 4
        for (int gi = 0; gi < 64; ++gi) {
            const int g = w * 64 + gi;
            float p = (l < CIN) ? w_ih[(size_t)g * CIN + l] * vl : 0.f;
            float tot = wave_sum_dpp(p);
            sq = fmaf(tot, tot, sq);
        }
        if (l == 63) red[w] = sq;
        __syncthreads();
        if (tid == 0) {
            float ns2 = 0.f;
            for (int i = 0; i < 8; ++i) ns2 += red[i];
            sigS[0] = ns2 / (sqrtf(ns2) + EPSF);
        }
        __syncthreads();
    }
    // ===== sigma_fc =====
    {
        red[tid] = (tid < 128) ? fc_w[tid] * fc_w[tid] : 0.f;
        __syncthreads();
        for (int s = 64; s >= 1; s >>= 1) { if (tid < s) red[tid] += red[tid + s]; __syncthreads(); }
        if (tid == 0) {
            float nw2 = red[0];
            float u0  = u_fc[0];
            float nv  = fabsf(u0) * sqrtf(nw2);
            float wv  = u0 * nw2 / (nv + EPSF);
            sigS[2]   = wv * wv / (fabsf(wv) + EPSF);
        }
        __syncthreads();
    }
    const float rih = 1.f / sigS[0];
    const float rhh = 1.f / sigS[1];
    const float rfc = 1.f / sigS[2];
    const float attb = attn_b[0];

    // ================= Phase C: weight conversion (R11) =================
    half8 Bf[4][5];
    float biasg[4], w32g[4];
#pragma unroll
    for (int p = 0; p < 4; ++p) {
        const int g = 16 * w + 128 * p + m;
#pragma unroll
        for (int kt = 0; kt < 4; ++kt) {
            const float* src = w_hh + (size_t)g * HH + kt * 32 + q * 8;
#pragma unroll
            for (int i = 0; i < 8; ++i) Bf[p][kt][i] = (_Float16)(src[i] * rhh);
        }
        {
            const float* src = w_ih + (size_t)g * CIN + q * 8;
#pragma unroll
            for (int i = 0; i < 8; ++i) Bf[p][4][i] = (_Float16)(src[i] * rih);
        }
        w32g[p]  = w_ih[(size_t)g * CIN + 32] * rih;
        biasg[p] = b_ih[g] + b_hh[g];
    }
    f32x4 zero4 = (f32x4){0.f, 0.f, 0.f, 0.f};
#pragma unroll
    for (int p = 0; p < 4; ++p) {
#pragma unroll
        for (int kt = 0; kt < 5; ++kt) asm volatile("" : "+v"(Bf[p][kt]));
        asm volatile("" : "+v"(biasg[p]), "+v"(w32g[p]));
    }
    asm volatile("" : "+v"(zero4));
    const float fcwj = fc_w[jcol] * rfc;
    const float aw0 = attn_w[2 * l];
    const float aw1 = attn_w[2 * l + 1];

    // ---- staging: A-row (0..31) = (k,rr) pair, row = 2k+rr; lane m holds
    //      row 16*mt+m -> k = 8*mt+(m>>1), rr = m&1. D rows q*4+j map back
    //      identically. gx includes bias + w32*s fold. ----
#define STAGE_LOAD(t0_, xr_)                                                   \
    {                                                                          \
        _Pragma("unroll")                                                      \
        for (int mt = 0; mt < 2; ++mt) {                                       \
            const size_t base =                                                \
                ((size_t)(b0 + (m & 1)) * TT + ((t0_) + 8 * mt + (m >> 1))) *  \
                    CC + q * 8;                                                \
            xr_[mt][0] = *reinterpret_cast<const float4*>(x + base);           \
            xr_[mt][1] = *reinterpret_cast<const float4*>(x + base + 4);       \
        }                                                                      \
    }

#define STAGE_COMMIT(t0_, nb_, xr_)                                            \
    {                                                                          \
        _Pragma("unroll")                                                      \
        for (int mt = 0; mt < 2; ++mt) {                                       \
            half8 af = {(_Float16)xr_[mt][0].x, (_Float16)xr_[mt][0].y,        \
                        (_Float16)xr_[mt][0].z, (_Float16)xr_[mt][0].w,        \
                        (_Float16)xr_[mt][1].x, (_Float16)xr_[mt][1].y,        \
                        (_Float16)xr_[mt][1].z, (_Float16)xr_[mt][1].w};       \
            f32x4 s0 = MFMA16H(af, Bf[0][4], zero4);                           \
            f32x4 s1 = MFMA16H(af, Bf[1][4], zero4);                           \
            f32x4 s2 = MFMA16H(af, Bf[2][4], zero4);                           \
            f32x4 s3 = MFMA16H(af, Bf[3][4], zero4);                           \
            const float svl = load_s(&ws[(t0_) + 8 * mt + 2 * q]);             \
            const float svh = load_s(&ws[(t0_) + 8 * mt + 2 * q + 1]);         \
            const int row0 = 16 * mt + 4 * q;                                  \
            _Pragma("unroll")                                                  \
            for (int j = 0; j < 4; ++j) {                                      \
                const float sv = (j & 2) ? svh : svl;                          \
                gxs[nb_][row0 + j][jcol + 0]   = s0[j] + fmaf(w32g[0], sv, biasg[0]); \
                gxs[nb_][row0 + j][jcol + 128] = s1[j] + fmaf(w32g[1], sv, biasg[1]); \
                gxs[nb_][row0 + j][jcol + 256] = s2[j] + fmaf(w32g[2], sv, biasg[2]); \
                gxs[nb_][row0 + j][jcol + 384] = s3[j] + fmaf(w32g[3], sv, biasg[3]); \
            }                                                                  \
        }                                                                      \
    }

    // One LSTM step: 16 MFMA (h-part only), gx add from LDS, raw barrier.
#define LSTM_STEP(t_, k_, cb_)                                                 \
    {                                                                          \
        const int t  = (t_);                                                   \
        const int hb = (t + 1) & 1;                                            \
        half8 ah0 = *(const half8*)&hs[hb][m & 1][0 * 32 + q * 8];             \
        half8 ah1 = *(const half8*)&hs[hb][m & 1][1 * 32 + q * 8];             \
        half8 ah2 = *(const half8*)&hs[hb][m & 1][2 * 32 + q * 8];             \
        half8 ah3 = *(const half8*)&hs[hb][m & 1][3 * 32 + q * 8];             \
        const float* gxr = &gxs[cb_][((k_) << 1) | r][jcol];                   \
        float gx0 = gxr[0];                                                    \
        float gx1 = gxr[128];                                                  \
        float gx2 = gxr[256];                                                  \
        float gx3 = gxr[384];                                                  \
        float dotp = 0.f;                                                      \
        if (t > 0 && w >= 6) {                                                 \
            half2v hh = *(const half2v*)&hs[hb][w - 6][2 * l];                 \
            dotp = fmaf(aw0, (float)hh[0], aw1 * (float)hh[1]);                \
        }                                                                      \
        if (t >= 2) P = fmaf(bcast[(t - 1) & 1][r], hpp, P);                   \
        f32x4 acc0 = MFMA16H(ah0, Bf[0][0], zero4);                            \
        f32x4 acc1 = MFMA16H(ah0, Bf[1][0], zero4);                            \
        f32x4 acc2 = MFMA16H(ah0, Bf[2][0], zero4);                            \
        f32x4 acc3 = MFMA16H(ah0, Bf[3][0], zero4);                            \
        acc0 = MFMA16H(ah1, Bf[0][1], acc0);                                   \
        acc1 = MFMA16H(ah1, Bf[1][1], acc1);                                   \
        acc2 = MFMA16H(ah1, Bf[2][1], acc2);                                   \
        acc3 = MFMA16H(ah1, Bf[3][1], acc3);                                   \
        acc0 = MFMA16H(ah2, Bf[0][2], acc0);                                   \
        acc1 = MFMA16H(ah2, Bf[1][2], acc1);                                   \
        acc2 = MFMA16H(ah2, Bf[2][2], acc2);                                   \
        acc3 = MFMA16H(ah2, Bf[3][2], acc3);                                   \
        acc0 = MFMA16H(ah3, Bf[0][3], acc0);                                   \
        acc1 = MFMA16H(ah3, Bf[1][3], acc1);                                   \
        acc2 = MFMA16H(ah3, Bf[2][3], acc2);                                   \
        acc3 = MFMA16H(ah3, Bf[3][3], acc3);                                   \
        if (t > 0 && w >= 6) {                                                 \
            float tot = wave_sum_dpp(dotp);                                    \
            if (l == 63) {                                                     \
                float beta = __expf(tot + attb);                               \
                Sreg += beta;                                                  \
                bcast[t & 1][w - 6] = beta;                                    \
            }                                                                  \
        }                                                                      \
        {                                                                      \
            float g0 = acc0[r] + gx0;                                          \
            float g1 = acc1[r] + gx1;                                          \
            float g2 = acc2[r] + gx2;                                          \
            float g3 = acc3[r] + gx3;                                          \
            float ig = fsig(g0);                                               \
            float fg = fsig(g1);                                               \
            float gg = ftanh(g2);                                              \
            float og = fsig(g3);                                               \
            c_st = fmaf(fg, c_st, ig * gg);                                    \
            float hv = og * ftanh(c_st);                                       \
            hpp   = hprev;                                                     \
            hprev = hv;                                                        \
            if (q < 2) hs[t & 1][r][jcol] = (_Float16)hv;                      \
        }                                                                      \
        BARRIER();                                                             \
    }

    // ================= Phase E: lstm main =================
    for (int i = tid; i < 2 * RB * HSP; i += 512) (&hs[0][0][0])[i] = (_Float16)0.f;

    float c_st = 0.f, P = 0.f, hprev = 0.f, hpp = 0.f;  // per-lane, row r
    float Sreg = 0.f;                                    // lane 63 of waves 6,7

    {   // chunk-0 gx staging (spins on ws published by all blocks' phase A)
        float4 xr0[2][2];
        STAGE_LOAD(0, xr0);
        STAGE_COMMIT(0, 0, xr0);
    }
    __syncthreads();

    for (int tc = 0; tc < NCH; ++tc) {
        const int cb  = tc & 1;
        const int t0n = (tc + 1) * CH;
        float4 xr[2][2];
        if (tc + 1 < NCH) STAGE_LOAD(t0n, xr);           // issue early (T14)
#pragma unroll 2
        for (int k = 0; k < CH / 2; ++k) LSTM_STEP(tc * CH + k, k, cb);
        if (tc + 1 < NCH) STAGE_COMMIT(t0n, cb ^ 1, xr); // commit mid-chunk
#pragma unroll 2
        for (int k = CH / 2; k < CH; ++k) LSTM_STEP(tc * CH + k, k, cb);
    }

    // ---- epilogue ----
    P = fmaf(bcast[1][r], hpp, P);
    if (w >= 6) {
        half2v hh = *(const half2v*)&hs[1][w - 6][2 * l];
        float dotp = fmaf(aw0, (float)hh[0], aw1 * (float)hh[1]);
        float tot = wave_sum_dpp(dotp);
        if (l == 63) {
            float beta = __expf(tot + attb);
            Sreg += beta;
            bcast[0][w - 6] = beta;
            Sf[w - 6] = Sreg;
        }
    }
    __syncthreads();
    {
        float Pv = fmaf(bcast[0][r], hprev, P);
        float v  = Pv * __builtin_amdgcn_rcpf(Sf[r]) * fcwj;
        float rs = row_sum_dpp(v);
        if (l == 15) part[w][0] = rs;       // row 0 sum (q=0)
        if (l == 31) part[w][1] = rs;       // row 1 sum (q=1)
    }
    __syncthreads();
    if (tid < RB) {
        float a = 0.f;
#pragma unroll
        for (int i = 0; i < 8; ++i) a += part[i][tid];
        out[b0 + tid] = a + fc_b[0];
    }
}

// ---------------------------------------------------------------------------
extern "C" void kernel_launch(void* const* d_in, const int* in_sizes, int n_in,
                              void* d_out, int out_size, void* d_ws, size_t ws_size,
                              hipStream_t stream) {
    const float* x      = (const float*)d_in[0];
    const float* w_ih   = (const float*)d_in[1];
    const float* u_ih   = (const float*)d_in[2];
    const float* w_hh   = (const float*)d_in[3];
    const float* u_hh   = (const float*)d_in[4];
    const float* b_ih   = (const float*)d_in[5];
    const float* b_hh   = (const float*)d_in[6];
    const float* attn_w = (const float*)d_in[7];
    const float* attn_b = (const float*)d_in[8];
    const float* fc_w   = (const float*)d_in[9];
    const float* u_fc   = (const float*)d_in[10];
    const float* fc_b   = (const float*)d_in[11];
    float* ws  = (float*)d_ws;
    float* out = (float*)d_out;

    critic_fused<<<BB / RB, 512, 0, stream>>>(x, w_ih, u_ih, w_hh, u_hh, b_ih, b_hh,
                                              attn_w, attn_b, fc_w, u_fc, fc_b, ws, out);
}